// Round 1
// baseline (467.973 us; speedup 1.0000x reference)
//
#include <hip/hip_runtime.h>
#include <hip/hip_bf16.h>

#define B_   4
#define S_   2048
#define E_   512
#define H_   8
#define D_   64
#define FFN_ 2304
#define M_   (B_*S_)   // 8192

typedef __attribute__((ext_vector_type(8))) short short8;
typedef __attribute__((ext_vector_type(4))) float f32x4;

__device__ __forceinline__ ushort f2bs(float f) {
  union { __hip_bfloat16 h; ushort u; } c; c.h = __float2bfloat16(f); return c.u;
}
__device__ __forceinline__ float bs2f(ushort u) {
  union { ushort u; __hip_bfloat16 h; } c; c.u = u; return __bfloat162float(c.h);
}
__device__ __forceinline__ f32x4 mfma16(short8 a, short8 b, f32x4 c) {
  return __builtin_amdgcn_mfma_f32_16x16x32_bf16(a, b, c, 0, 0, 0);
}
__device__ __forceinline__ void gload_lds16(const ushort* g, ushort* l) {
  __builtin_amdgcn_global_load_lds(
      (const __attribute__((address_space(1))) unsigned int*)g,
      (__attribute__((address_space(3))) unsigned int*)l, 16, 0, 0);
}

// ---------------- weight fp32 -> bf16 ----------------
__global__ __launch_bounds__(256) void f2b_kernel(const float* __restrict__ src,
                                                  ushort* __restrict__ dst, int n4) {
  int i = blockIdx.x * 256 + threadIdx.x;
  if (i < n4) {
    float4 v = ((const float4*)src)[i];
    ushort4 o;
    o.x = f2bs(v.x); o.y = f2bs(v.y); o.z = f2bs(v.z); o.w = f2bs(v.w);
    ((ushort4*)dst)[i] = o;
  }
}

// ---------------- cos/sin table [S][64] ----------------
__global__ __launch_bounds__(256) void cstab_kernel(float2* __restrict__ tab) {
  int idx = blockIdx.x * 256 + threadIdx.x;   // 0..131071
  int s = idx >> 6, d = idx & 63;
  float freq = powf(10000.f, -(float)(d & 31) * (1.f/32.f));
  float ang = (float)s * freq;
  float sn, cs;
  sincosf(ang, &sn, &cs);
  tab[idx] = make_float2(cs, sn);
}

// ---------------- RMSNorm: fp32 in -> bf16 out ----------------
__global__ __launch_bounds__(256) void rmsnorm_kernel(const float* __restrict__ x,
                                                      const float* __restrict__ w,
                                                      ushort* __restrict__ out) {
  const int row = blockIdx.x * 4 + (threadIdx.x >> 6);
  const int lane = threadIdx.x & 63;
  const float* xr = x + (size_t)row * E_ + lane * 8;
  float4 v0 = *(const float4*)xr;
  float4 v1 = *(const float4*)(xr + 4);
  float ss = v0.x*v0.x + v0.y*v0.y + v0.z*v0.z + v0.w*v0.w
           + v1.x*v1.x + v1.y*v1.y + v1.z*v1.z + v1.w*v1.w;
  #pragma unroll
  for (int m = 1; m < 64; m <<= 1) ss += __shfl_xor(ss, m, 64);
  float r = rsqrtf(ss * (1.f/(float)E_) + 1e-6f);
  const float* wp = w + lane * 8;
  ushort4 o0, o1;
  o0.x = f2bs(v0.x*r*wp[0]); o0.y = f2bs(v0.y*r*wp[1]);
  o0.z = f2bs(v0.z*r*wp[2]); o0.w = f2bs(v0.w*r*wp[3]);
  o1.x = f2bs(v1.x*r*wp[4]); o1.y = f2bs(v1.y*r*wp[5]);
  o1.z = f2bs(v1.z*r*wp[6]); o1.w = f2bs(v1.w*r*wp[7]);
  ushort* o = out + (size_t)row * E_ + lane * 8;
  *(ushort4*)o = o0;
  *(ushort4*)(o + 4) = o1;
}

// ---------------- RoPE in-place on qkv (q and k slices) ----------------
__global__ __launch_bounds__(256) void rope_kernel(ushort* __restrict__ qkv,
                                                   const float2* __restrict__ tab) {
  int idx = blockIdx.x * 256 + threadIdx.x;  // < 4194304
  int i     = idx & 31;
  int hh    = (idx >> 5) & 7;
  int which = (idx >> 8) & 1;
  int s     = (idx >> 9) & 2047;
  int b     = idx >> 20;
  ushort* base = qkv + ((size_t)(b * S_ + s)) * (3*E_) + which * E_ + hh * D_;
  float x0 = bs2f(base[2*i]), x1 = bs2f(base[2*i+1]);
  float2 cs0 = tab[s*64 + 2*i];
  float2 cs1 = tab[s*64 + 2*i + 1];
  base[2*i]   = f2bs(x0*cs0.x - x1*cs0.y);   // x0*cos + (-x1)*sin
  base[2*i+1] = f2bs(x1*cs1.x + x0*cs1.y);   // x1*cos + ( x0)*sin
}

// ---------------- causal flash attention ----------------
// grid (S/64, B*H), block 256 (4 waves x 16 q-rows). qkv layout [B,S,3,H,D] bf16.
__global__ __launch_bounds__(256) void attn_kernel(const ushort* __restrict__ qkv,
                                                   ushort* __restrict__ ctx) {
  const int qb = blockIdx.x;
  const int bh = blockIdx.y;
  const int b = bh >> 3, h = bh & 7;
  const int tid = threadIdx.x;
  const int w = tid >> 6;
  const int lane = tid & 63;
  const int l16 = lane & 15;
  const int hi = lane >> 4;

  __shared__ ushort Ks[64][72];
  __shared__ ushort Vt[64][72];        // V transposed: Vt[d][kk]
  __shared__ ushort Ps[4][16][72];     // per-wave P tile [q_local][kk]

  const size_t bbase = (size_t)b * S_ * (3*E_);
  const int q0 = qb*64 + w*16 + l16;
  short8 qf0, qf1;
  {
    const ushort* qrow = qkv + bbase + (size_t)q0 * (3*E_) + h*D_;
    qf0 = *(const short8*)(qrow + hi*8);
    qf1 = *(const short8*)(qrow + 32 + hi*8);
  }
  f32x4 acc[4];
  #pragma unroll
  for (int d = 0; d < 4; ++d) acc[d] = (f32x4){0.f,0.f,0.f,0.f};
  float mrun[4] = {-1e30f,-1e30f,-1e30f,-1e30f};
  float lrun[4] = {0.f,0.f,0.f,0.f};

  const int stg_kk = tid >> 3;         // 0..31
  const int stg_c  = (tid & 7) * 8;

  for (int t = 0; t <= qb; ++t) {
    __syncthreads();   // protect K/V LDS from previous iteration's readers
    #pragma unroll
    for (int r = 0; r < 2; ++r) {
      int kk = stg_kk + r*32;
      const ushort* krow = qkv + bbase + (size_t)(t*64 + kk)*(3*E_) + E_ + h*D_ + stg_c;
      *(short8*)&Ks[kk][stg_c] = *(const short8*)krow;
      const ushort* vrow = qkv + bbase + (size_t)(t*64 + kk)*(3*E_) + 2*E_ + h*D_ + stg_c;
      short8 v8 = *(const short8*)vrow;
      #pragma unroll
      for (int u = 0; u < 8; ++u) Vt[stg_c + u][kk] = (ushort)v8[u];
    }
    __syncthreads();

    // scores: 16 q-rows x 64 k-cols per wave
    float sc[4][4];
    #pragma unroll
    for (int s4 = 0; s4 < 4; ++s4) {
      f32x4 a = (f32x4){0.f,0.f,0.f,0.f};
      short8 kf0 = *(const short8*)&Ks[s4*16 + l16][hi*8];
      short8 kf1 = *(const short8*)&Ks[s4*16 + l16][32 + hi*8];
      a = mfma16(qf0, kf0, a);
      a = mfma16(qf1, kf1, a);
      #pragma unroll
      for (int j = 0; j < 4; ++j) sc[s4][j] = a[j] * 0.125f;
    }
    if (t == qb) {
      #pragma unroll
      for (int s4 = 0; s4 < 4; ++s4)
        #pragma unroll
        for (int j = 0; j < 4; ++j)
          if (s4*16 + l16 > w*16 + hi*4 + j) sc[s4][j] = -1e30f;
    }
    // online softmax (rows: hi*4+j, cols distributed over 16 lanes)
    float mt[4], pv[4][4], ls[4], alpha[4];
    #pragma unroll
    for (int j = 0; j < 4; ++j)
      mt[j] = fmaxf(fmaxf(sc[0][j], sc[1][j]), fmaxf(sc[2][j], sc[3][j]));
    #pragma unroll
    for (int msk = 1; msk <= 8; msk <<= 1)
      #pragma unroll
      for (int j = 0; j < 4; ++j) mt[j] = fmaxf(mt[j], __shfl_xor(mt[j], msk, 64));
    #pragma unroll
    for (int j = 0; j < 4; ++j) {
      float mn = fmaxf(mrun[j], mt[j]);
      alpha[j] = __expf(mrun[j] - mn);
      mrun[j] = mn;
      ls[j] = 0.f;
      #pragma unroll
      for (int s4 = 0; s4 < 4; ++s4) { pv[s4][j] = __expf(sc[s4][j] - mn); ls[j] += pv[s4][j]; }
    }
    #pragma unroll
    for (int msk = 1; msk <= 8; msk <<= 1)
      #pragma unroll
      for (int j = 0; j < 4; ++j) ls[j] += __shfl_xor(ls[j], msk, 64);
    #pragma unroll
    for (int j = 0; j < 4; ++j) lrun[j] = lrun[j]*alpha[j] + ls[j];
    #pragma unroll
    for (int d = 0; d < 4; ++d)
      #pragma unroll
      for (int j = 0; j < 4; ++j) acc[d][j] *= alpha[j];
    // P -> LDS (bf16) to re-fragment for PV
    #pragma unroll
    for (int s4 = 0; s4 < 4; ++s4)
      #pragma unroll
      for (int j = 0; j < 4; ++j)
        Ps[w][hi*4 + j][s4*16 + l16] = f2bs(pv[s4][j]);
    short8 pf0 = *(const short8*)&Ps[w][l16][hi*8];
    short8 pf1 = *(const short8*)&Ps[w][l16][32 + hi*8];
    #pragma unroll
    for (int d = 0; d < 4; ++d) {
      short8 vf0 = *(const short8*)&Vt[d*16 + l16][hi*8];
      short8 vf1 = *(const short8*)&Vt[d*16 + l16][32 + hi*8];
      acc[d] = mfma16(pf0, vf0, acc[d]);
      acc[d] = mfma16(pf1, vf1, acc[d]);
    }
  }
  #pragma unroll
  for (int j = 0; j < 4; ++j) lrun[j] = 1.f / lrun[j];
  #pragma unroll
  for (int d = 0; d < 4; ++d)
    #pragma unroll
    for (int j = 0; j < 4; ++j) {
      int srow = qb*64 + w*16 + hi*4 + j;
      int dcol = d*16 + l16;
      ctx[((size_t)(b * S_ + srow)) * E_ + h*D_ + dcol] = f2bs(acc[d][j] * lrun[j]);
    }
}

// ---------------- GEMM: C[M,N] = A[M,K] @ W[N,K]^T (both bf16, row-major over K)
// MODE 0: store bf16   MODE 1: fp32 + residual(aux fp32)
// MODE 2: store bf16 silu(acc)   MODE 3: store bf16 acc*aux(bf16)
template<int MODE>
__global__ __launch_bounds__(256) void gemm_bt(const ushort* __restrict__ A,
                                               const ushort* __restrict__ W,
                                               void* __restrict__ outp,
                                               const void* __restrict__ aux,
                                               int M, int N, int K) {
  __shared__ ushort As[128*32];
  __shared__ ushort Bs[128*32];
  const int tid = threadIdx.x;
  const int lane = tid & 63;
  const int w = tid >> 6;
  const int wr = w >> 1, wc = w & 1;
  const int l16 = lane & 15, hi = lane >> 4;
  const int bm = blockIdx.y, bn = blockIdx.x;

  f32x4 acc[4][4];
  #pragma unroll
  for (int m = 0; m < 4; ++m)
    #pragma unroll
    for (int n = 0; n < 4; ++n) acc[m][n] = (f32x4){0.f,0.f,0.f,0.f};

  const int srow = tid >> 2;
  const int scol = (tid & 3) * 8;
  const ushort* ga = A + (size_t)(bm*128 + srow) * K + scol;
  const ushort* gb = W + (size_t)(bn*128 + srow) * K + scol;

  for (int k0 = 0; k0 < K; k0 += 32) {
    gload_lds16(ga + k0,                 &As[tid*8]);
    gload_lds16(ga + k0 + (size_t)64*K,  &As[2048 + tid*8]);
    gload_lds16(gb + k0,                 &Bs[tid*8]);
    gload_lds16(gb + k0 + (size_t)64*K,  &Bs[2048 + tid*8]);
    __syncthreads();
    short8 af[4], bf[4];
    #pragma unroll
    for (int m = 0; m < 4; ++m)
      af[m] = *(const short8*)&As[(wr*64 + m*16 + l16)*32 + hi*8];
    #pragma unroll
    for (int n = 0; n < 4; ++n)
      bf[n] = *(const short8*)&Bs[(wc*64 + n*16 + l16)*32 + hi*8];
    #pragma unroll
    for (int m = 0; m < 4; ++m)
      #pragma unroll
      for (int n = 0; n < 4; ++n)
        acc[m][n] = mfma16(af[m], bf[n], acc[m][n]);
    __syncthreads();
  }
  #pragma unroll
  for (int m = 0; m < 4; ++m)
    #pragma unroll
    for (int n = 0; n < 4; ++n)
      #pragma unroll
      for (int j = 0; j < 4; ++j) {
        int row = bm*128 + wr*64 + m*16 + hi*4 + j;
        int col = bn*128 + wc*64 + n*16 + l16;
        size_t o = (size_t)row * N + col;
        float v = acc[m][n][j];
        if (MODE == 0)      ((ushort*)outp)[o] = f2bs(v);
        else if (MODE == 1) ((float*)outp)[o] = v + ((const float*)aux)[o];
        else if (MODE == 2) ((ushort*)outp)[o] = f2bs(v / (1.f + __expf(-v)));
        else                ((ushort*)outp)[o] = f2bs(v * bs2f(((const ushort*)aux)[o]));
      }
}

extern "C" void kernel_launch(void* const* d_in, const int* in_sizes, int n_in,
                              void* d_out, int out_size, void* d_ws, size_t ws_size,
                              hipStream_t stream) {
  const float* x      = (const float*)d_in[0];
  const float* qkv_w  = (const float*)d_in[1];
  const float* out_w  = (const float*)d_in[2];
  const float* n1_w   = (const float*)d_in[3];
  const float* n2_w   = (const float*)d_in[4];
  const float* gate_w = (const float*)d_in[5];
  const float* up_w   = (const float*)d_in[6];
  const float* down_w = (const float*)d_in[7];
  float* outp = (float*)d_out;

  char* ws = (char*)d_ws;
  ushort* wqkv  = (ushort*)ws; ws += (size_t)1536*512*2;
  ushort* wout  = (ushort*)ws; ws += (size_t)512*512*2;
  ushort* wgate = (ushort*)ws; ws += (size_t)2304*512*2;
  ushort* wup   = (ushort*)ws; ws += (size_t)2304*512*2;
  ushort* wdown = (ushort*)ws; ws += (size_t)512*2304*2;
  ushort* h     = (ushort*)ws; ws += (size_t)M_*E_*2;
  ushort* qkv   = (ushort*)ws; ws += (size_t)M_*1536*2;
  ushort* ctx   = (ushort*)ws; ws += (size_t)M_*E_*2;
  ushort* ffn   = (ushort*)ws; ws += (size_t)M_*FFN_*2;
  float2* tab   = (float2*)ws; ws += (size_t)S_*64*8;

  f2b_kernel<<<768, 256, 0, stream>>>(qkv_w, wqkv, 1536*512/4);
  f2b_kernel<<<256, 256, 0, stream>>>(out_w, wout, 512*512/4);
  f2b_kernel<<<1152, 256, 0, stream>>>(gate_w, wgate, 2304*512/4);
  f2b_kernel<<<1152, 256, 0, stream>>>(up_w, wup, 2304*512/4);
  f2b_kernel<<<1152, 256, 0, stream>>>(down_w, wdown, 512*2304/4);
  cstab_kernel<<<512, 256, 0, stream>>>(tab);

  // h = rmsnorm(x, n1)
  rmsnorm_kernel<<<M_/4, 256, 0, stream>>>(x, n1_w, h);
  // qkv = h @ qkv_w^T  (bf16 out)
  gemm_bt<0><<<dim3(1536/128, M_/128), 256, 0, stream>>>(h, wqkv, qkv, nullptr, M_, 1536, 512);
  // rope in place on q,k
  rope_kernel<<<(B_*S_*2*H_*32)/256, 256, 0, stream>>>(qkv, tab);
  // ctx = attention
  attn_kernel<<<dim3(S_/64, B_*H_), 256, 0, stream>>>(qkv, ctx);
  // d_out = x + ctx @ out_w^T
  gemm_bt<1><<<dim3(512/128, M_/128), 256, 0, stream>>>(ctx, wout, outp, x, M_, 512, 512);
  // h = rmsnorm(d_out, n2)
  rmsnorm_kernel<<<M_/4, 256, 0, stream>>>(outp, n2_w, h);
  // ffn = silu(h @ gate^T)
  gemm_bt<2><<<dim3(2304/128, M_/128), 256, 0, stream>>>(h, wgate, ffn, nullptr, M_, 2304, 512);
  // ffn = ffn * (h @ up^T)
  gemm_bt<3><<<dim3(2304/128, M_/128), 256, 0, stream>>>(h, wup, ffn, ffn, M_, 2304, 512);
  // d_out = d_out + ffn @ down^T
  gemm_bt<1><<<dim3(512/128, M_/128), 256, 0, stream>>>(ffn, wdown, outp, outp, M_, 512, 2304);
}

// Round 2
// 415.915 us; speedup vs baseline: 1.1252x; 1.1252x over previous
//
#include <hip/hip_runtime.h>
#include <hip/hip_bf16.h>

#define B_   4
#define S_   2048
#define E_   512
#define H_   8
#define D_   64
#define FFN_ 2304
#define M_   (B_*S_)   // 8192

typedef __attribute__((ext_vector_type(8))) short short8;
typedef __attribute__((ext_vector_type(4))) float f32x4;

__device__ __forceinline__ ushort f2bs(float f) {
  union { __hip_bfloat16 h; ushort u; } c; c.h = __float2bfloat16(f); return c.u;
}
__device__ __forceinline__ float bs2f(ushort u) {
  union { ushort u; __hip_bfloat16 h; } c; c.u = u; return __bfloat162float(c.h);
}
__device__ __forceinline__ f32x4 mfma16(short8 a, short8 b, f32x4 c) {
  return __builtin_amdgcn_mfma_f32_16x16x32_bf16(a, b, c, 0, 0, 0);
}
__device__ __forceinline__ void gload_lds16(const ushort* g, ushort* l) {
  __builtin_amdgcn_global_load_lds(
      (const __attribute__((address_space(1))) unsigned int*)g,
      (__attribute__((address_space(3))) unsigned int*)l, 16, 0, 0);
}

// ---------------- weight fp32 -> bf16 ----------------
__global__ __launch_bounds__(256) void f2b_kernel(const float* __restrict__ src,
                                                  ushort* __restrict__ dst, int n4) {
  int i = blockIdx.x * 256 + threadIdx.x;
  if (i < n4) {
    float4 v = ((const float4*)src)[i];
    ushort4 o;
    o.x = f2bs(v.x); o.y = f2bs(v.y); o.z = f2bs(v.z); o.w = f2bs(v.w);
    ((ushort4*)dst)[i] = o;
  }
}

// ---------------- cos/sin table [S][64] ----------------
__global__ __launch_bounds__(256) void cstab_kernel(float2* __restrict__ tab) {
  int idx = blockIdx.x * 256 + threadIdx.x;   // 0..131071
  int s = idx >> 6, d = idx & 63;
  float freq = powf(10000.f, -(float)(d & 31) * (1.f/32.f));
  float ang = (float)s * freq;
  float sn, cs;
  sincosf(ang, &sn, &cs);
  tab[idx] = make_float2(cs, sn);
}

// ---------------- RMSNorm: fp32 in -> bf16 out ----------------
__global__ __launch_bounds__(256) void rmsnorm_kernel(const float* __restrict__ x,
                                                      const float* __restrict__ w,
                                                      ushort* __restrict__ out) {
  const int row = blockIdx.x * 4 + (threadIdx.x >> 6);
  const int lane = threadIdx.x & 63;
  const float* xr = x + (size_t)row * E_ + lane * 8;
  float4 v0 = *(const float4*)xr;
  float4 v1 = *(const float4*)(xr + 4);
  float ss = v0.x*v0.x + v0.y*v0.y + v0.z*v0.z + v0.w*v0.w
           + v1.x*v1.x + v1.y*v1.y + v1.z*v1.z + v1.w*v1.w;
  #pragma unroll
  for (int m = 1; m < 64; m <<= 1) ss += __shfl_xor(ss, m, 64);
  float r = rsqrtf(ss * (1.f/(float)E_) + 1e-6f);
  const float* wp = w + lane * 8;
  ushort4 o0, o1;
  o0.x = f2bs(v0.x*r*wp[0]); o0.y = f2bs(v0.y*r*wp[1]);
  o0.z = f2bs(v0.z*r*wp[2]); o0.w = f2bs(v0.w*r*wp[3]);
  o1.x = f2bs(v1.x*r*wp[4]); o1.y = f2bs(v1.y*r*wp[5]);
  o1.z = f2bs(v1.z*r*wp[6]); o1.w = f2bs(v1.w*r*wp[7]);
  ushort* o = out + (size_t)row * E_ + lane * 8;
  *(ushort4*)o = o0;
  *(ushort4*)(o + 4) = o1;
}

// ---------------- RoPE in-place on qkv (q and k slices) ----------------
__global__ __launch_bounds__(256) void rope_kernel(ushort* __restrict__ qkv,
                                                   const float2* __restrict__ tab) {
  int idx = blockIdx.x * 256 + threadIdx.x;  // < 4194304
  int i     = idx & 31;
  int hh    = (idx >> 5) & 7;
  int which = (idx >> 8) & 1;
  int s     = (idx >> 9) & 2047;
  int b     = idx >> 20;
  ushort* base = qkv + ((size_t)(b * S_ + s)) * (3*E_) + which * E_ + hh * D_;
  float x0 = bs2f(base[2*i]), x1 = bs2f(base[2*i+1]);
  float2 cs0 = tab[s*64 + 2*i];
  float2 cs1 = tab[s*64 + 2*i + 1];
  base[2*i]   = f2bs(x0*cs0.x - x1*cs0.y);
  base[2*i+1] = f2bs(x1*cs1.x + x0*cs1.y);
}

// ---------------- V transpose: qkv V-slice -> Vg[b][h][d][s] ----------------
// grid (S/64, B*H), block 256. XOR-swizzled LDS to avoid column-read conflicts.
__global__ __launch_bounds__(256) void vtrans_kernel(const ushort* __restrict__ qkv,
                                                     ushort* __restrict__ vg) {
  __shared__ ushort Vs[64][72];
  const int s0 = blockIdx.x * 64;
  const int bh = blockIdx.y;
  const int b = bh >> 3, h = bh & 7;
  const int tid = threadIdx.x;
  const int r = tid >> 3, c = (tid & 7) * 8;    // r 0..31, c 0..56
  const size_t base = (size_t)b * S_ * 1536 + 2*E_ + h*64;
  #pragma unroll
  for (int half = 0; half < 2; ++half) {
    int rr = r + half*32;
    const ushort* src = qkv + base + (size_t)(s0 + rr) * 1536 + c;
    // swizzle: column-chunk c stored at c ^ (8*((rr>>3)&7))
    *(short8*)&Vs[rr][c ^ (8*((rr>>3)&7))] = *(const short8*)src;
  }
  __syncthreads();
  #pragma unroll
  for (int half = 0; half < 2; ++half) {
    int d = r + half*32;
    short8 o;
    #pragma unroll
    for (int u = 0; u < 8; ++u) {
      int row = c + u;
      o[u] = (short)Vs[row][d ^ (8*((row>>3)&7))];
    }
    *(short8*)(vg + ((size_t)(bh*64 + d))*S_ + s0 + c) = o;
  }
}

// ---------------- causal flash attention ----------------
// grid 512 (= B*H * S/128), block 256 = 4 waves x 32 q-rows each. KVBLK=64.
__global__ __launch_bounds__(256) void attn_kernel(const ushort* __restrict__ qkv,
                                                   const ushort* __restrict__ vg,
                                                   ushort* __restrict__ ctx) {
  const int qb = 15 - (blockIdx.x & 15);     // long blocks first
  const int bh = blockIdx.x >> 4;
  const int b = bh >> 3, h = bh & 7;
  const int tid = threadIdx.x;
  const int w = tid >> 6;
  const int lane = tid & 63;
  const int l16 = lane & 15;
  const int hi = lane >> 4;

  __shared__ ushort Ks[64][72];
  __shared__ ushort Vt[64][72];     // V^T tile: Vt[d][kk]
  __shared__ ushort Ps[4][32][72];  // per-wave P: [q_local][k_local]

  const size_t bbase = (size_t)b * S_ * 1536;
  const int qrow0 = qb*128 + w*32;

  short8 qf[2][2];
  #pragma unroll
  for (int m = 0; m < 2; ++m) {
    const ushort* qr = qkv + bbase + (size_t)(qrow0 + m*16 + l16) * 1536 + h*64;
    qf[m][0] = *(const short8*)(qr + hi*8);
    qf[m][1] = *(const short8*)(qr + 32 + hi*8);
  }

  f32x4 acc[2][4];
  #pragma unroll
  for (int m = 0; m < 2; ++m)
    #pragma unroll
    for (int d = 0; d < 4; ++d) acc[m][d] = (f32x4){0.f,0.f,0.f,0.f};
  float mrun[2][4], lrun[2][4];
  #pragma unroll
  for (int m = 0; m < 2; ++m)
    #pragma unroll
    for (int j = 0; j < 4; ++j) { mrun[m][j] = -1e30f; lrun[m][j] = 0.f; }

  const int sr = tid >> 2;          // 0..63
  const int sc = (tid & 3) * 16;    // 0,16,32,48
  const int nt = 2*qb + 2;

  for (int t = 0; t < nt; ++t) {
    __syncthreads();
    {
      const ushort* kr = qkv + bbase + (size_t)(t*64 + sr)*1536 + E_ + h*64 + sc;
      *(short8*)&Ks[sr][sc]     = *(const short8*)kr;
      *(short8*)&Ks[sr][sc + 8] = *(const short8*)(kr + 8);
      const ushort* vr = vg + ((size_t)(bh*64 + sr))*S_ + t*64 + sc;
      *(short8*)&Vt[sr][sc]     = *(const short8*)vr;
      *(short8*)&Vt[sr][sc + 8] = *(const short8*)(vr + 8);
    }
    __syncthreads();
    if (t*64 > qrow0 + 31) continue;   // whole tile masked for this wave

    // ---- QK^T: 16 MFMAs ----
    float scr[2][4][4];
    #pragma unroll
    for (int s4 = 0; s4 < 4; ++s4) {
      short8 kf0 = *(const short8*)&Ks[s4*16 + l16][hi*8];
      short8 kf1 = *(const short8*)&Ks[s4*16 + l16][32 + hi*8];
      #pragma unroll
      for (int m = 0; m < 2; ++m) {
        f32x4 a = (f32x4){0.f,0.f,0.f,0.f};
        a = mfma16(qf[m][0], kf0, a);
        a = mfma16(qf[m][1], kf1, a);
        #pragma unroll
        for (int j = 0; j < 4; ++j) scr[m][s4][j] = a[j] * 0.125f;
      }
    }
    if (t*64 + 63 > qrow0) {
      #pragma unroll
      for (int m = 0; m < 2; ++m)
        #pragma unroll
        for (int s4 = 0; s4 < 4; ++s4)
          #pragma unroll
          for (int j = 0; j < 4; ++j)
            if (t*64 + s4*16 + l16 > qrow0 + m*16 + hi*4 + j) scr[m][s4][j] = -1e30f;
    }

    // ---- online softmax ----
    #pragma unroll
    for (int m = 0; m < 2; ++m) {
      float mt[4];
      #pragma unroll
      for (int j = 0; j < 4; ++j)
        mt[j] = fmaxf(fmaxf(scr[m][0][j], scr[m][1][j]), fmaxf(scr[m][2][j], scr[m][3][j]));
      #pragma unroll
      for (int msk = 1; msk <= 8; msk <<= 1)
        #pragma unroll
        for (int j = 0; j < 4; ++j) mt[j] = fmaxf(mt[j], __shfl_xor(mt[j], msk, 64));
      float ls[4], alpha[4];
      float pv[4][4];
      #pragma unroll
      for (int j = 0; j < 4; ++j) {
        float mn = fmaxf(mrun[m][j], mt[j]);
        alpha[j] = __expf(mrun[m][j] - mn);
        mrun[m][j] = mn;
        ls[j] = 0.f;
        #pragma unroll
        for (int s4 = 0; s4 < 4; ++s4) { pv[s4][j] = __expf(scr[m][s4][j] - mn); ls[j] += pv[s4][j]; }
      }
      #pragma unroll
      for (int msk = 1; msk <= 8; msk <<= 1)
        #pragma unroll
        for (int j = 0; j < 4; ++j) ls[j] += __shfl_xor(ls[j], msk, 64);
      #pragma unroll
      for (int j = 0; j < 4; ++j) lrun[m][j] = lrun[m][j]*alpha[j] + ls[j];
      #pragma unroll
      for (int d = 0; d < 4; ++d)
        #pragma unroll
        for (int j = 0; j < 4; ++j) acc[m][d][j] *= alpha[j];
      #pragma unroll
      for (int s4 = 0; s4 < 4; ++s4)
        #pragma unroll
        for (int j = 0; j < 4; ++j)
          Ps[w][m*16 + hi*4 + j][s4*16 + l16] = f2bs(pv[s4][j]);
    }

    // ---- PV: 16 MFMAs ----
    short8 pf[2][2];
    #pragma unroll
    for (int m = 0; m < 2; ++m) {
      pf[m][0] = *(const short8*)&Ps[w][m*16 + l16][hi*8];
      pf[m][1] = *(const short8*)&Ps[w][m*16 + l16][32 + hi*8];
    }
    #pragma unroll
    for (int d = 0; d < 4; ++d) {
      short8 vf0 = *(const short8*)&Vt[d*16 + l16][hi*8];
      short8 vf1 = *(const short8*)&Vt[d*16 + l16][32 + hi*8];
      #pragma unroll
      for (int m = 0; m < 2; ++m) {
        acc[m][d] = mfma16(pf[m][0], vf0, acc[m][d]);
        acc[m][d] = mfma16(pf[m][1], vf1, acc[m][d]);
      }
    }
  }

  #pragma unroll
  for (int m = 0; m < 2; ++m)
    #pragma unroll
    for (int j = 0; j < 4; ++j) {
      float inv = 1.f / lrun[m][j];
      int srow = qrow0 + m*16 + hi*4 + j;
      #pragma unroll
      for (int d = 0; d < 4; ++d)
        ctx[((size_t)(b * S_ + srow)) * E_ + h*D_ + d*16 + l16] = f2bs(acc[m][d][j] * inv);
    }
}

// ---------------- GEMM: C[M,N] = A[M,K] @ W[N,K]^T (both bf16)
// MODE 0: store bf16   MODE 1: fp32 + residual(aux fp32)
// MODE 2: store bf16 silu(acc)   MODE 3: store bf16 acc*aux(bf16)
template<int MODE>
__global__ __launch_bounds__(256) void gemm_bt(const ushort* __restrict__ A,
                                               const ushort* __restrict__ W,
                                               void* __restrict__ outp,
                                               const void* __restrict__ aux,
                                               int M, int N, int K) {
  __shared__ ushort As[128*32];
  __shared__ ushort Bs[128*32];
  const int tid = threadIdx.x;
  const int lane = tid & 63;
  const int w = tid >> 6;
  const int wr = w >> 1, wc = w & 1;
  const int l16 = lane & 15, hi = lane >> 4;
  const int bm = blockIdx.y, bn = blockIdx.x;

  f32x4 acc[4][4];
  #pragma unroll
  for (int m = 0; m < 4; ++m)
    #pragma unroll
    for (int n = 0; n < 4; ++n) acc[m][n] = (f32x4){0.f,0.f,0.f,0.f};

  const int srow = tid >> 2;
  const int scol = (tid & 3) * 8;
  const ushort* ga = A + (size_t)(bm*128 + srow) * K + scol;
  const ushort* gb = W + (size_t)(bn*128 + srow) * K + scol;

  for (int k0 = 0; k0 < K; k0 += 32) {
    gload_lds16(ga + k0,                 &As[tid*8]);
    gload_lds16(ga + k0 + (size_t)64*K,  &As[2048 + tid*8]);
    gload_lds16(gb + k0,                 &Bs[tid*8]);
    gload_lds16(gb + k0 + (size_t)64*K,  &Bs[2048 + tid*8]);
    __syncthreads();
    short8 af[4], bf[4];
    #pragma unroll
    for (int m = 0; m < 4; ++m)
      af[m] = *(const short8*)&As[(wr*64 + m*16 + l16)*32 + hi*8];
    #pragma unroll
    for (int n = 0; n < 4; ++n)
      bf[n] = *(const short8*)&Bs[(wc*64 + n*16 + l16)*32 + hi*8];
    #pragma unroll
    for (int m = 0; m < 4; ++m)
      #pragma unroll
      for (int n = 0; n < 4; ++n)
        acc[m][n] = mfma16(af[m], bf[n], acc[m][n]);
    __syncthreads();
  }
  #pragma unroll
  for (int m = 0; m < 4; ++m)
    #pragma unroll
    for (int n = 0; n < 4; ++n)
      #pragma unroll
      for (int j = 0; j < 4; ++j) {
        int row = bm*128 + wr*64 + m*16 + hi*4 + j;
        int col = bn*128 + wc*64 + n*16 + l16;
        size_t o = (size_t)row * N + col;
        float v = acc[m][n][j];
        if (MODE == 0)      ((ushort*)outp)[o] = f2bs(v);
        else if (MODE == 1) ((float*)outp)[o] = v + ((const float*)aux)[o];
        else if (MODE == 2) ((ushort*)outp)[o] = f2bs(v / (1.f + __expf(-v)));
        else                ((ushort*)outp)[o] = f2bs(v * bs2f(((const ushort*)aux)[o]));
      }
}

extern "C" void kernel_launch(void* const* d_in, const int* in_sizes, int n_in,
                              void* d_out, int out_size, void* d_ws, size_t ws_size,
                              hipStream_t stream) {
  const float* x      = (const float*)d_in[0];
  const float* qkv_w  = (const float*)d_in[1];
  const float* out_w  = (const float*)d_in[2];
  const float* n1_w   = (const float*)d_in[3];
  const float* n2_w   = (const float*)d_in[4];
  const float* gate_w = (const float*)d_in[5];
  const float* up_w   = (const float*)d_in[6];
  const float* down_w = (const float*)d_in[7];
  float* outp = (float*)d_out;

  char* ws = (char*)d_ws;
  ushort* wqkv  = (ushort*)ws; ws += (size_t)1536*512*2;
  ushort* wout  = (ushort*)ws; ws += (size_t)512*512*2;
  ushort* wgate = (ushort*)ws; ws += (size_t)2304*512*2;
  ushort* wup   = (ushort*)ws; ws += (size_t)2304*512*2;
  ushort* wdown = (ushort*)ws; ws += (size_t)512*2304*2;
  ushort* h     = (ushort*)ws; ws += (size_t)M_*E_*2;
  ushort* qkv   = (ushort*)ws; ws += (size_t)M_*1536*2;
  ushort* ctx   = (ushort*)ws; ws += (size_t)M_*E_*2;
  ushort* ffn   = (ushort*)ws; ws += (size_t)M_*FFN_*2;
  float2* tab   = (float2*)ws; ws += (size_t)S_*64*8;
  ushort* vgt   = (ushort*)ffn;   // alias: vgt dead before ffn is written

  f2b_kernel<<<768, 256, 0, stream>>>(qkv_w, wqkv, 1536*512/4);
  f2b_kernel<<<256, 256, 0, stream>>>(out_w, wout, 512*512/4);
  f2b_kernel<<<1152, 256, 0, stream>>>(gate_w, wgate, 2304*512/4);
  f2b_kernel<<<1152, 256, 0, stream>>>(up_w, wup, 2304*512/4);
  f2b_kernel<<<1152, 256, 0, stream>>>(down_w, wdown, 512*2304/4);
  cstab_kernel<<<512, 256, 0, stream>>>(tab);

  rmsnorm_kernel<<<M_/4, 256, 0, stream>>>(x, n1_w, h);
  gemm_bt<0><<<dim3(1536/128, M_/128), 256, 0, stream>>>(h, wqkv, qkv, nullptr, M_, 1536, 512);
  rope_kernel<<<(B_*S_*2*H_*32)/256, 256, 0, stream>>>(qkv, tab);
  vtrans_kernel<<<dim3(S_/64, B_*H_), 256, 0, stream>>>(qkv, vgt);
  attn_kernel<<<512, 256, 0, stream>>>(qkv, vgt, ctx);
  gemm_bt<1><<<dim3(512/128, M_/128), 256, 0, stream>>>(ctx, wout, outp, x, M_, 512, 512);
  rmsnorm_kernel<<<M_/4, 256, 0, stream>>>(outp, n2_w, h);
  gemm_bt<2><<<dim3(2304/128, M_/128), 256, 0, stream>>>(h, wgate, ffn, nullptr, M_, 2304, 512);
  gemm_bt<3><<<dim3(2304/128, M_/128), 256, 0, stream>>>(h, wup, ffn, ffn, M_, 2304, 512);
  gemm_bt<1><<<dim3(512/128, M_/128), 256, 0, stream>>>(ffn, wdown, outp, outp, M_, 512, 2304);
}